// Round 5
// baseline (625.656 us; speedup 1.0000x reference)
//
#include <hip/hip_runtime.h>
#include <hip/hip_bf16.h>

// Problem constants (match reference)
constexpr int N   = 50000;
constexpr int R   = 51;
constexpr int E   = 16;
constexpr int C   = 8;
constexpr int B   = 40;
constexpr int NNZ = 1600000;

// Bucketed counting sort: 64 nodes/bucket -> LDS-resident accumulators
constexpr int BSH  = 6;
constexpr int BKN  = 1 << BSH;               // 64
constexpr int NB   = (N + BKN - 1) >> BSH;   // 782
constexpr int NB2  = NB / 2;                 // 391 (split point)
constexpr int NPAD = NB * BKN;               // 50048
constexpr int KS   = 4;                      // k-split for layer kernels

constexpr int CBLK   = 784;
constexpr int CCHUNK = (NNZ + CBLK - 1) / CBLK;   // 2041
constexpr int SBLK   = 256;
constexpr int SCHUNK = (NNZ + SBLK - 1) / SBLK;   // 6250
constexpr int PSCAP  = 2816;   // psort LDS record capacity (mean 2046, +17 sigma)
constexpr int CMASK  = (1 << 26) - 1;

// ---------------------------------------------------------------------------
// K1: W1 = comps1(R,B) @ bases1(B,N*E), bf16-packed rows (32B per (p,o) row).
//     Split into 2 dispatches by column half (visibility; no extra traffic).
// ---------------------------------------------------------------------------
__global__ __launch_bounds__(256) void w1_gemm_kernel(
    const float* __restrict__ comps1, const float* __restrict__ bases1,
    unsigned* __restrict__ W1u, int jbase, int jend) {
  constexpr int NC2 = N * E / 2;  // 400000 pair-columns
  int j = jbase + blockIdx.x * 256 + threadIdx.x;
  if (j >= jend) return;
  const float2* b2 = reinterpret_cast<const float2*>(bases1);
  float2 col[B];
#pragma unroll
  for (int b = 0; b < B; ++b) col[b] = b2[b * NC2 + j];
#pragma unroll 1
  for (int r = 0; r < R; ++r) {
    float ax = 0.f, ay = 0.f;
#pragma unroll
    for (int b = 0; b < B; ++b) {
      float cc = comps1[r * B + b];   // block-uniform -> scalar loads
      ax = fmaf(cc, col[b].x, ax);
      ay = fmaf(cc, col[b].y, ay);
    }
    unsigned lo = __bfloat16_as_ushort(__float2bfloat16(ax));
    unsigned hi = __bfloat16_as_ushort(__float2bfloat16(ay));
    W1u[r * NC2 + j] = (hi << 16) | lo;
  }
}

// ---------------------------------------------------------------------------
// K2: bucket histogram
// ---------------------------------------------------------------------------
__global__ __launch_bounds__(256) void count_kernel(
    const int* __restrict__ rows, int* __restrict__ gcount) {
  __shared__ int hist[NB];
  for (int i = threadIdx.x; i < NB; i += 256) hist[i] = 0;
  __syncthreads();
  int lo = blockIdx.x * CCHUNK;
  int hi = lo + CCHUNK < NNZ ? lo + CCHUNK : NNZ;
  for (int i = lo + threadIdx.x; i < hi; i += 256)
    atomicAdd(&hist[rows[i] >> BSH], 1);
  __syncthreads();
  for (int i = threadIdx.x; i < NB; i += 256)
    if (hist[i]) atomicAdd(&gcount[i], hist[i]);
}

// ---------------------------------------------------------------------------
// K3: scan -> gstart[NB+1], gcursor[NB]
// ---------------------------------------------------------------------------
__global__ __launch_bounds__(1024) void scan_kernel(
    const int* __restrict__ gcount, int* __restrict__ gstart,
    int* __restrict__ gcursor) {
  __shared__ int buf[1024];
  int t = threadIdx.x;
  int own = (t < NB) ? gcount[t] : 0;
  buf[t] = own;
  __syncthreads();
  for (int d = 1; d < 1024; d <<= 1) {
    int v = (t >= d) ? buf[t - d] : 0;
    __syncthreads();
    buf[t] += v;
    __syncthreads();
  }
  if (t < NB) {
    int st = buf[t] - own;
    gstart[t] = st;
    gcursor[t] = st;
  }
  if (t == NB - 1) gstart[NB] = buf[t];
}

// ---------------------------------------------------------------------------
// K4: scatter into bucket-grouped packed records (8B):
//     word0 = (s_lo<<26) | col, word1 = val bits
// ---------------------------------------------------------------------------
__global__ __launch_bounds__(256) void scatter_kernel(
    const int* __restrict__ rows, const int* __restrict__ cols,
    const float* __restrict__ vals, int* __restrict__ gcursor,
    int2* __restrict__ packed) {
  __shared__ int hist[NB];
  __shared__ int base[NB];
  for (int i = threadIdx.x; i < NB; i += 256) hist[i] = 0;
  __syncthreads();
  int lo = blockIdx.x * SCHUNK;
  int hi = lo + SCHUNK < NNZ ? lo + SCHUNK : NNZ;
  for (int i = lo + threadIdx.x; i < hi; i += 256)
    atomicAdd(&hist[rows[i] >> BSH], 1);
  __syncthreads();
  for (int i = threadIdx.x; i < NB; i += 256) {
    int c = hist[i];
    base[i] = c ? atomicAdd(&gcursor[i], c) : 0;
  }
  __syncthreads();
  for (int i = threadIdx.x; i < NB; i += 256) hist[i] = 0;  // reuse as cursor
  __syncthreads();
  for (int i = lo + threadIdx.x; i < hi; i += 256) {
    int s = rows[i];
    int b = s >> BSH;
    int pos = base[b] + atomicAdd(&hist[b], 1);
    packed[pos] = make_int2(((s & (BKN - 1)) << 26) | cols[i],
                            __float_as_int(vals[i]));
  }
}

// ---------------------------------------------------------------------------
// K4b: in-place per-bucket counting sort by relation p.
//      Makes layer2's per-lane p wave-uniform -> LDS broadcast, no conflicts.
//      Order within a bucket is irrelevant for correctness (pure sum).
// ---------------------------------------------------------------------------
__global__ __launch_bounds__(256) void psort_kernel(
    const int* __restrict__ gstart, long long* __restrict__ packed) {
  __shared__ long long buf[PSCAP];
  __shared__ int cnt[R + 1];
  __shared__ int base[R + 1];
  int bkt = blockIdx.x;
  int lo = gstart[bkt], len = gstart[bkt + 1] - lo;
  if (len > PSCAP) return;  // never for this data; correctness-safe fallback
  if (threadIdx.x < R + 1) cnt[threadIdx.x] = 0;
  __syncthreads();
  for (int i = threadIdx.x; i < len; i += 256) {
    long long r = packed[lo + i];
    buf[i] = r;
    int p = (int)((unsigned)((int)r & CMASK) / (unsigned)N);
    atomicAdd(&cnt[p], 1);
  }
  __syncthreads();
  if (threadIdx.x == 0) {
    int run = 0;
    for (int p = 0; p < R; ++p) { base[p] = run; run += cnt[p]; }
  }
  __syncthreads();
  if (threadIdx.x < R + 1) cnt[threadIdx.x] = 0;  // reuse as cursor
  __syncthreads();
  for (int i = threadIdx.x; i < len; i += 256) {
    long long r = buf[i];
    int p = (int)((unsigned)((int)r & CMASK) / (unsigned)N);
    int pos = base[p] + atomicAdd(&cnt[p], 1);
    packed[lo + pos] = r;   // scattered 8B within a 16KB region: L2-combined
  }
}

// ---------------------------------------------------------------------------
// K5: W2 = comps2 @ bases2 (tiny)
// ---------------------------------------------------------------------------
__global__ void w2_gemm_kernel(const float* __restrict__ comps2,
                               const float* __restrict__ bases2,
                               float* __restrict__ W2g) {
  int i = blockIdx.x * blockDim.x + threadIdx.x;
  if (i >= R * E * C) return;
  int r = i >> 7;
  int ec = i & 127;
  float acc = 0.f;
#pragma unroll
  for (int b = 0; b < B; ++b)
    acc = fmaf(comps2[r * B + b], bases2[b * 128 + ec], acc);
  W2g[i] = acc;
}

// ---------------------------------------------------------------------------
// K6: layer 1. KS=4 (full grid depth, round-3 occupancy) + 2-consecutive-edge
//     unroll per thread (4 outstanding dwordx4 row gathers).
// ---------------------------------------------------------------------------
__device__ __forceinline__ void l1_accum(float* hp, float v, uint4 w0, uint4 w1) {
  atomicAdd(hp + 0,  v * __uint_as_float(w0.x << 16));
  atomicAdd(hp + 1,  v * __uint_as_float(w0.x & 0xffff0000u));
  atomicAdd(hp + 2,  v * __uint_as_float(w0.y << 16));
  atomicAdd(hp + 3,  v * __uint_as_float(w0.y & 0xffff0000u));
  atomicAdd(hp + 4,  v * __uint_as_float(w0.z << 16));
  atomicAdd(hp + 5,  v * __uint_as_float(w0.z & 0xffff0000u));
  atomicAdd(hp + 6,  v * __uint_as_float(w0.w << 16));
  atomicAdd(hp + 7,  v * __uint_as_float(w0.w & 0xffff0000u));
  atomicAdd(hp + 8,  v * __uint_as_float(w1.x << 16));
  atomicAdd(hp + 9,  v * __uint_as_float(w1.x & 0xffff0000u));
  atomicAdd(hp + 10, v * __uint_as_float(w1.y << 16));
  atomicAdd(hp + 11, v * __uint_as_float(w1.y & 0xffff0000u));
  atomicAdd(hp + 12, v * __uint_as_float(w1.z << 16));
  atomicAdd(hp + 13, v * __uint_as_float(w1.z & 0xffff0000u));
  atomicAdd(hp + 14, v * __uint_as_float(w1.w << 16));
  atomicAdd(hp + 15, v * __uint_as_float(w1.w & 0xffff0000u));
}

__global__ __launch_bounds__(256) void layer1_kernel(
    const unsigned* __restrict__ W1u, const int* __restrict__ gstart,
    const int2* __restrict__ packed, float* __restrict__ hpart, int bkt_base) {
  __shared__ float hacc[BKN * 17];
  for (int i = threadIdx.x; i < BKN * 17; i += 256) hacc[i] = 0.f;
  __syncthreads();
  int bkt = bkt_base + (blockIdx.x >> 2), part = blockIdx.x & 3;
  int lo = gstart[bkt], len = gstart[bkt + 1] - lo;
  int a = lo + ((len * part) >> 2), b = lo + ((len * (part + 1)) >> 2);
  int plen = b - a;
  const uint4* W14 = reinterpret_cast<const uint4*>(W1u);
  const long long* pk8 = reinterpret_cast<const long long*>(packed);
  // main loop: 2 consecutive edges per thread
  for (int e = a + 2 * (int)threadIdx.x; e + 1 < b; e += 512) {
    long long r0 = __builtin_nontemporal_load(pk8 + e);
    long long r1 = __builtin_nontemporal_load(pk8 + e + 1);
    int m0 = (int)r0, m1 = (int)r1;
    int c0 = m0 & CMASK, c1 = m1 & CMASK;
    uint4 wa0 = W14[c0 * 2 + 0], wa1 = W14[c0 * 2 + 1];
    uint4 wb0 = W14[c1 * 2 + 0], wb1 = W14[c1 * 2 + 1];
    l1_accum(&hacc[(((unsigned)m0) >> 26) * 17], __int_as_float((int)(r0 >> 32)), wa0, wa1);
    l1_accum(&hacc[(((unsigned)m1) >> 26) * 17], __int_as_float((int)(r1 >> 32)), wb0, wb1);
  }
  // tail: at most one leftover edge
  int m = a + ((plen >> 1) << 1);
  for (int e = m + (int)threadIdx.x; e < b; e += 256) {
    long long r0 = __builtin_nontemporal_load(pk8 + e);
    int m0 = (int)r0;
    int c0 = m0 & CMASK;
    uint4 w0 = W14[c0 * 2 + 0], w1 = W14[c0 * 2 + 1];
    l1_accum(&hacc[(((unsigned)m0) >> 26) * 17], __int_as_float((int)(r0 >> 32)), w0, w1);
  }
  __syncthreads();
  float* dst = hpart + (size_t)part * (NPAD * E) + ((size_t)bkt << BSH) * E;
  for (int i = threadIdx.x; i < BKN * E; i += 256) {
    int slo = i >> 4, ee = i & 15;
    dst[i] = hacc[slo * 17 + ee];
  }
}

// ---------------------------------------------------------------------------
// K7: h = relu(sum_part hpart + bias1)
// ---------------------------------------------------------------------------
__global__ __launch_bounds__(256) void relu_kernel(
    const float* __restrict__ hpart, const float* __restrict__ bias1,
    float* __restrict__ h) {
  int i = blockIdx.x * 256 + threadIdx.x;
  if (i >= N * E / 4) return;
  constexpr int P4 = NPAD * E / 4;
  const float4* hp = reinterpret_cast<const float4*>(hpart);
  float4 s0 = hp[i], s1 = hp[i + P4], s2 = hp[i + 2 * P4], s3 = hp[i + 3 * P4];
  float4 bb = reinterpret_cast<const float4*>(bias1)[i & 3];
  float4 r;
  r.x = fmaxf(s0.x + s1.x + s2.x + s3.x + bb.x, 0.f);
  r.y = fmaxf(s0.y + s1.y + s2.y + s3.y + bb.y, 0.f);
  r.z = fmaxf(s0.z + s1.z + s2.z + s3.z + bb.z, 0.f);
  r.w = fmaxf(s0.w + s1.w + s2.w + s3.w + bb.w, 0.f);
  reinterpret_cast<float4*>(h)[i] = r;
}

// ---------------------------------------------------------------------------
// K8: layer 2. KS=4 + 2-consecutive-edge unroll. After psort, per-lane p is
//     (near-)wave-uniform -> w2s reads broadcast (conflict-free).
// ---------------------------------------------------------------------------
__device__ __forceinline__ void l2_accum(float* op, float v, float4 h0,
                                         float4 h1, float4 h2, float4 h3,
                                         const float* w2s, int p) {
  const float4* wp = reinterpret_cast<const float4*>(w2s + p * 132);
#pragma unroll
  for (int c = 0; c < 8; ++c) {
    float4 aq = wp[c * 4 + 0];
    float4 bq = wp[c * 4 + 1];
    float4 cq = wp[c * 4 + 2];
    float4 dq = wp[c * 4 + 3];
    float s = h0.x * aq.x + h0.y * aq.y + h0.z * aq.z + h0.w * aq.w
            + h1.x * bq.x + h1.y * bq.y + h1.z * bq.z + h1.w * bq.w
            + h2.x * cq.x + h2.y * cq.y + h2.z * cq.z + h2.w * cq.w
            + h3.x * dq.x + h3.y * dq.y + h3.z * dq.z + h3.w * dq.w;
    atomicAdd(op + c, v * s);
  }
}

__global__ __launch_bounds__(256) void layer2_kernel(
    const float* __restrict__ h, const float* __restrict__ W2g,
    const int* __restrict__ gstart, const int2* __restrict__ packed,
    float* __restrict__ opart, int bkt_base) {
  __shared__ float w2s[R * 132];
  __shared__ float oacc[BKN * 9];
  for (int i = threadIdx.x; i < R * E * C; i += 256) {
    int p = i >> 7, ec = i & 127;     // W2g layout [p][e][c]
    int e = ec >> 3, c = ec & 7;
    w2s[p * 132 + c * 16 + e] = W2g[i];
  }
  for (int i = threadIdx.x; i < BKN * 9; i += 256) oacc[i] = 0.f;
  __syncthreads();
  int bkt = bkt_base + (blockIdx.x >> 2), part = blockIdx.x & 3;
  int lo = gstart[bkt], len = gstart[bkt + 1] - lo;
  int a = lo + ((len * part) >> 2), b = lo + ((len * (part + 1)) >> 2);
  int plen = b - a;
  const float4* H4 = reinterpret_cast<const float4*>(h);
  const long long* pk8 = reinterpret_cast<const long long*>(packed);
  for (int e = a + 2 * (int)threadIdx.x; e + 1 < b; e += 512) {
    long long r0 = __builtin_nontemporal_load(pk8 + e);
    long long r1 = __builtin_nontemporal_load(pk8 + e + 1);
    int m0 = (int)r0, m1 = (int)r1;
    int col0 = m0 & CMASK, col1 = m1 & CMASK;
    int p0 = (int)((unsigned)col0 / (unsigned)N);
    int o0 = col0 - p0 * N;
    int p1 = (int)((unsigned)col1 / (unsigned)N);
    int o1 = col1 - p1 * N;
    float4 a0 = H4[o0 * 4 + 0], a1 = H4[o0 * 4 + 1];
    float4 a2 = H4[o0 * 4 + 2], a3 = H4[o0 * 4 + 3];
    float4 b0 = H4[o1 * 4 + 0], b1 = H4[o1 * 4 + 1];
    float4 b2 = H4[o1 * 4 + 2], b3 = H4[o1 * 4 + 3];
    l2_accum(&oacc[(((unsigned)m0) >> 26) * 9], __int_as_float((int)(r0 >> 32)),
             a0, a1, a2, a3, w2s, p0);
    l2_accum(&oacc[(((unsigned)m1) >> 26) * 9], __int_as_float((int)(r1 >> 32)),
             b0, b1, b2, b3, w2s, p1);
  }
  int m = a + ((plen >> 1) << 1);
  for (int e = m + (int)threadIdx.x; e < b; e += 256) {
    long long r0 = __builtin_nontemporal_load(pk8 + e);
    int m0 = (int)r0;
    int col0 = m0 & CMASK;
    int p0 = (int)((unsigned)col0 / (unsigned)N);
    int o0 = col0 - p0 * N;
    float4 a0 = H4[o0 * 4 + 0], a1 = H4[o0 * 4 + 1];
    float4 a2 = H4[o0 * 4 + 2], a3 = H4[o0 * 4 + 3];
    l2_accum(&oacc[(((unsigned)m0) >> 26) * 9], __int_as_float((int)(r0 >> 32)),
             a0, a1, a2, a3, w2s, p0);
  }
  __syncthreads();
  float* dst = opart + (size_t)part * (NPAD * C) + ((size_t)bkt << BSH) * C;
  for (int i = threadIdx.x; i < BKN * C; i += 256) {
    int slo = i >> 3, c = i & 7;
    dst[i] = oacc[slo * 9 + c];
  }
}

// ---------------------------------------------------------------------------
// K9: out = sum_part opart + bias2
// ---------------------------------------------------------------------------
__global__ __launch_bounds__(256) void out_kernel(
    const float* __restrict__ opart, const float* __restrict__ bias2,
    float* __restrict__ out) {
  int i = blockIdx.x * 256 + threadIdx.x;
  if (i >= N * C / 4) return;
  constexpr int P4 = NPAD * C / 4;
  const float4* op = reinterpret_cast<const float4*>(opart);
  float4 s0 = op[i], s1 = op[i + P4], s2 = op[i + 2 * P4], s3 = op[i + 3 * P4];
  float4 bb = reinterpret_cast<const float4*>(bias2)[i & 1];
  float4 r;
  r.x = s0.x + s1.x + s2.x + s3.x + bb.x;
  r.y = s0.y + s1.y + s2.y + s3.y + bb.y;
  r.z = s0.z + s1.z + s2.z + s3.z + bb.z;
  r.w = s0.w + s1.w + s2.w + s3.w + bb.w;
  reinterpret_cast<float4*>(out)[i] = r;
}

// ---------------------------------------------------------------------------
extern "C" void kernel_launch(void* const* d_in, const int* in_sizes, int n_in,
                              void* d_out, int out_size, void* d_ws, size_t ws_size,
                              hipStream_t stream) {
  const float* values  = (const float*)d_in[0];
  const float* comps1  = (const float*)d_in[1];
  const float* bases1  = (const float*)d_in[2];
  const float* comps2  = (const float*)d_in[3];
  const float* bases2  = (const float*)d_in[4];
  const float* bias1   = (const float*)d_in[5];
  const float* bias2   = (const float*)d_in[6];
  const int* hor_rows  = (const int*)d_in[7];
  const int* hor_cols  = (const int*)d_in[8];
  float* out = (float*)d_out;

  char* ws = (char*)d_ws;
  size_t off = 0;
  auto alloc = [&](size_t bytes) {
    void* p = ws + off;
    off += (bytes + 255) & ~size_t(255);
    return p;
  };
  unsigned* W1u    = (unsigned*)alloc((size_t)R * N * E / 2 * 4);   // 81.6 MB
  float*    h      = (float*)alloc((size_t)N * E * 4);              // 3.2 MB
  float*    W2g    = (float*)alloc((size_t)R * E * C * 4);
  int*      gcount = (int*)alloc((size_t)NB * 4);
  int*      gstart = (int*)alloc((size_t)(NB + 1) * 4);
  int*      gcursor= (int*)alloc((size_t)NB * 4);
  int2*     packed = (int2*)alloc((size_t)NNZ * 8);                 // 12.8 MB
  float*    hpart  = (float*)alloc((size_t)KS * NPAD * E * 4);      // 12.8 MB
  float*    opart  = (float*)alloc((size_t)KS * NPAD * C * 4);      // 6.4 MB
  (void)ws_size; (void)in_sizes; (void)n_in; (void)out_size;

  hipMemsetAsync(gcount, 0, (size_t)NB * 4, stream);

  count_kernel<<<CBLK, 256, 0, stream>>>(hor_rows, gcount);
  scan_kernel<<<1, 1024, 0, stream>>>(gcount, gstart, gcursor);
  scatter_kernel<<<SBLK, 256, 0, stream>>>(hor_rows, hor_cols, values, gcursor,
                                           packed);
  psort_kernel<<<NB, 256, 0, stream>>>(gstart, (long long*)packed);
  w2_gemm_kernel<<<(R * E * C + 255) / 256, 256, 0, stream>>>(comps2, bases2, W2g);
  // split dispatches: per-instance durations become visible in top-5 profile
  w1_gemm_kernel<<<782, 256, 0, stream>>>(comps1, bases1, W1u, 0, 200000);
  w1_gemm_kernel<<<782, 256, 0, stream>>>(comps1, bases1, W1u, 200000, 400000);
  layer1_kernel<<<NB2 * KS, 256, 0, stream>>>(W1u, gstart, packed, hpart, 0);
  layer1_kernel<<<(NB - NB2) * KS, 256, 0, stream>>>(W1u, gstart, packed, hpart, NB2);
  relu_kernel<<<(N * E / 4 + 255) / 256, 256, 0, stream>>>(hpart, bias1, h);
  layer2_kernel<<<NB2 * KS, 256, 0, stream>>>(h, W2g, gstart, packed, opart, 0);
  layer2_kernel<<<(NB - NB2) * KS, 256, 0, stream>>>(h, W2g, gstart, packed, opart, NB2);
  out_kernel<<<(N * C / 4 + 255) / 256, 256, 0, stream>>>(opart, bias2, out);
}

// Round 7
// 563.448 us; speedup vs baseline: 1.1104x; 1.1104x over previous
//
#include <hip/hip_runtime.h>
#include <hip/hip_bf16.h>

// Problem constants (match reference)
constexpr int N   = 50000;
constexpr int R   = 51;
constexpr int E   = 16;
constexpr int C   = 8;
constexpr int B   = 40;
constexpr int NNZ = 1600000;

// Bucketed counting sort: 64 nodes/bucket -> LDS-resident accumulators
constexpr int BSH  = 6;
constexpr int BKN  = 1 << BSH;               // 64
constexpr int NB   = (N + BKN - 1) >> BSH;   // 782
constexpr int NPAD = NB * BKN;               // 50048
constexpr int KS1  = 8;                      // k-split layer1 (occupancy)
constexpr int KS2  = 4;                      // k-split layer2

constexpr int CBLK   = 784;
constexpr int CCHUNK = (NNZ + CBLK - 1) / CBLK;   // 2041
constexpr int SBLK   = 256;
constexpr int SCHUNK = (NNZ + SBLK - 1) / SBLK;   // 6250
constexpr int PSCAP  = 2816;   // psort LDS capacity (mean 2046, +17 sigma)
constexpr int CMASK  = (1 << 26) - 1;

// ---------------------------------------------------------------------------
// K1: W1 = comps1(R,B) @ bases1(B,N*E), bf16-packed rows (32B per (p,o) row)
// ---------------------------------------------------------------------------
__global__ __launch_bounds__(256) void w1_gemm_kernel(
    const float* __restrict__ comps1, const float* __restrict__ bases1,
    unsigned* __restrict__ W1u) {
  constexpr int NC2 = N * E / 2;  // 400000 pair-columns
  int j = blockIdx.x * 256 + threadIdx.x;
  if (j >= NC2) return;
  const float2* b2 = reinterpret_cast<const float2*>(bases1);
  float2 col[B];
#pragma unroll
  for (int b = 0; b < B; ++b) col[b] = b2[b * NC2 + j];
#pragma unroll 1
  for (int r = 0; r < R; ++r) {
    float ax = 0.f, ay = 0.f;
#pragma unroll
    for (int b = 0; b < B; ++b) {
      float cc = comps1[r * B + b];   // block-uniform -> scalar loads
      ax = fmaf(cc, col[b].x, ax);
      ay = fmaf(cc, col[b].y, ay);
    }
    unsigned lo = __bfloat16_as_ushort(__float2bfloat16(ax));
    unsigned hi = __bfloat16_as_ushort(__float2bfloat16(ay));
    W1u[r * NC2 + j] = (hi << 16) | lo;
  }
}

// ---------------------------------------------------------------------------
// K2: bucket histogram
// ---------------------------------------------------------------------------
__global__ __launch_bounds__(256) void count_kernel(
    const int* __restrict__ rows, int* __restrict__ gcount) {
  __shared__ int hist[NB];
  for (int i = threadIdx.x; i < NB; i += 256) hist[i] = 0;
  __syncthreads();
  int lo = blockIdx.x * CCHUNK;
  int hi = lo + CCHUNK < NNZ ? lo + CCHUNK : NNZ;
  for (int i = lo + threadIdx.x; i < hi; i += 256)
    atomicAdd(&hist[rows[i] >> BSH], 1);
  __syncthreads();
  for (int i = threadIdx.x; i < NB; i += 256)
    if (hist[i]) atomicAdd(&gcount[i], hist[i]);
}

// ---------------------------------------------------------------------------
// K3: scan -> gstart[NB+1], gcursor[NB]
// ---------------------------------------------------------------------------
__global__ __launch_bounds__(1024) void scan_kernel(
    const int* __restrict__ gcount, int* __restrict__ gstart,
    int* __restrict__ gcursor) {
  __shared__ int buf[1024];
  int t = threadIdx.x;
  int own = (t < NB) ? gcount[t] : 0;
  buf[t] = own;
  __syncthreads();
  for (int d = 1; d < 1024; d <<= 1) {
    int v = (t >= d) ? buf[t - d] : 0;
    __syncthreads();
    buf[t] += v;
    __syncthreads();
  }
  if (t < NB) {
    int st = buf[t] - own;
    gstart[t] = st;
    gcursor[t] = st;
  }
  if (t == NB - 1) gstart[NB] = buf[t];
}

// ---------------------------------------------------------------------------
// K4: scatter into bucket-grouped packed records (8B):
//     word0 = (s_lo<<26) | col, word1 = val bits. 1024 thr/block (occupancy).
// ---------------------------------------------------------------------------
__global__ __launch_bounds__(1024) void scatter_kernel(
    const int* __restrict__ rows, const int* __restrict__ cols,
    const float* __restrict__ vals, int* __restrict__ gcursor,
    int2* __restrict__ packed) {
  __shared__ int hist[NB];
  __shared__ int base[NB];
  for (int i = threadIdx.x; i < NB; i += 1024) hist[i] = 0;
  __syncthreads();
  int lo = blockIdx.x * SCHUNK;
  int hi = lo + SCHUNK < NNZ ? lo + SCHUNK : NNZ;
  for (int i = lo + threadIdx.x; i < hi; i += 1024)
    atomicAdd(&hist[rows[i] >> BSH], 1);
  __syncthreads();
  for (int i = threadIdx.x; i < NB; i += 1024) {
    int c = hist[i];
    base[i] = c ? atomicAdd(&gcursor[i], c) : 0;
  }
  __syncthreads();
  for (int i = threadIdx.x; i < NB; i += 1024) hist[i] = 0;  // reuse as cursor
  __syncthreads();
  for (int i = lo + threadIdx.x; i < hi; i += 1024) {
    int s = rows[i];
    int b = s >> BSH;
    int pos = base[b] + atomicAdd(&hist[b], 1);
    packed[pos] = make_int2(((s & (BKN - 1)) << 26) | cols[i],
                            __float_as_int(vals[i]));
  }
}

// ---------------------------------------------------------------------------
// K4b: in-place per-bucket counting sort by relation p (layer2 LDS broadcast
//      + slight L2 locality for layer1). Order irrelevant for correctness.
// ---------------------------------------------------------------------------
__global__ __launch_bounds__(256) void psort_kernel(
    const int* __restrict__ gstart, long long* __restrict__ packed) {
  __shared__ long long buf[PSCAP];
  __shared__ int cnt[R + 1];
  __shared__ int base[R + 1];
  int bkt = blockIdx.x;
  int lo = gstart[bkt], len = gstart[bkt + 1] - lo;
  if (len > PSCAP) return;  // statistically never; correctness-safe fallback
  if (threadIdx.x < R + 1) cnt[threadIdx.x] = 0;
  __syncthreads();
  for (int i = threadIdx.x; i < len; i += 256) {
    long long r = packed[lo + i];
    buf[i] = r;
    int p = (int)((unsigned)((int)r & CMASK) / (unsigned)N);
    atomicAdd(&cnt[p], 1);
  }
  __syncthreads();
  if (threadIdx.x == 0) {
    int run = 0;
    for (int p = 0; p < R; ++p) { base[p] = run; run += cnt[p]; }
  }
  __syncthreads();
  if (threadIdx.x < R + 1) cnt[threadIdx.x] = 0;  // reuse as cursor
  __syncthreads();
  for (int i = threadIdx.x; i < len; i += 256) {
    long long r = buf[i];
    int p = (int)((unsigned)((int)r & CMASK) / (unsigned)N);
    int pos = base[p] + atomicAdd(&cnt[p], 1);
    packed[lo + pos] = r;   // 8B scattered within 16KB region: L2-combined
  }
}

// ---------------------------------------------------------------------------
// K5: W2 = comps2 @ bases2 (tiny)
// ---------------------------------------------------------------------------
__global__ void w2_gemm_kernel(const float* __restrict__ comps2,
                               const float* __restrict__ bases2,
                               float* __restrict__ W2g) {
  int i = blockIdx.x * blockDim.x + threadIdx.x;
  if (i >= R * E * C) return;
  int r = i >> 7;
  int ec = i & 127;
  float acc = 0.f;
#pragma unroll
  for (int b = 0; b < B; ++b)
    acc = fmaf(comps2[r * B + b], bases2[b * 128 + ec], acc);
  W2g[i] = acc;
}

// ---------------------------------------------------------------------------
// K6: layer 1. KS1=8 -> 6256 blocks (deep grid, max resident waves).
//     1 edge/thread/iter: pk load + 2 dwordx4 row loads in flight.
// ---------------------------------------------------------------------------
__device__ __forceinline__ void l1_accum(float* hp, float v, uint4 w0, uint4 w1) {
  atomicAdd(hp + 0,  v * __uint_as_float(w0.x << 16));
  atomicAdd(hp + 1,  v * __uint_as_float(w0.x & 0xffff0000u));
  atomicAdd(hp + 2,  v * __uint_as_float(w0.y << 16));
  atomicAdd(hp + 3,  v * __uint_as_float(w0.y & 0xffff0000u));
  atomicAdd(hp + 4,  v * __uint_as_float(w0.z << 16));
  atomicAdd(hp + 5,  v * __uint_as_float(w0.z & 0xffff0000u));
  atomicAdd(hp + 6,  v * __uint_as_float(w0.w << 16));
  atomicAdd(hp + 7,  v * __uint_as_float(w0.w & 0xffff0000u));
  atomicAdd(hp + 8,  v * __uint_as_float(w1.x << 16));
  atomicAdd(hp + 9,  v * __uint_as_float(w1.x & 0xffff0000u));
  atomicAdd(hp + 10, v * __uint_as_float(w1.y << 16));
  atomicAdd(hp + 11, v * __uint_as_float(w1.y & 0xffff0000u));
  atomicAdd(hp + 12, v * __uint_as_float(w1.z << 16));
  atomicAdd(hp + 13, v * __uint_as_float(w1.z & 0xffff0000u));
  atomicAdd(hp + 14, v * __uint_as_float(w1.w << 16));
  atomicAdd(hp + 15, v * __uint_as_float(w1.w & 0xffff0000u));
}

__global__ __launch_bounds__(256) void layer1_kernel(
    const unsigned* __restrict__ W1u, const int* __restrict__ gstart,
    const int2* __restrict__ packed, float* __restrict__ hpart) {
  __shared__ float hacc[BKN * 17];
  for (int i = threadIdx.x; i < BKN * 17; i += 256) hacc[i] = 0.f;
  __syncthreads();
  int bkt = blockIdx.x >> 3, part = blockIdx.x & (KS1 - 1);
  int lo = gstart[bkt], len = gstart[bkt + 1] - lo;
  int a = lo + ((len * part) >> 3), b = lo + ((len * (part + 1)) >> 3);
  const uint4* W14 = reinterpret_cast<const uint4*>(W1u);
  const long long* pk8 = reinterpret_cast<const long long*>(packed);
  for (int e = a + (int)threadIdx.x; e < b; e += 256) {
    long long r0 = __builtin_nontemporal_load(pk8 + e);
    int m0 = (int)r0;
    int c0 = m0 & CMASK;
    uint4 w0 = W14[c0 * 2 + 0], w1 = W14[c0 * 2 + 1];
    l1_accum(&hacc[(((unsigned)m0) >> 26) * 17], __int_as_float((int)(r0 >> 32)),
             w0, w1);
  }
  __syncthreads();
  float* dst = hpart + (size_t)part * (NPAD * E) + ((size_t)bkt << BSH) * E;
  for (int i = threadIdx.x; i < BKN * E; i += 256) {
    int slo = i >> 4, ee = i & 15;
    __builtin_nontemporal_store(hacc[slo * 17 + ee], dst + i);
  }
}

// ---------------------------------------------------------------------------
// K7: h = relu(sum over 8 parts of hpart + bias1)
// ---------------------------------------------------------------------------
__global__ __launch_bounds__(256) void relu_kernel(
    const float* __restrict__ hpart, const float* __restrict__ bias1,
    float* __restrict__ h) {
  int i = blockIdx.x * 256 + threadIdx.x;
  if (i >= N * E / 4) return;
  constexpr int P4 = NPAD * E / 4;
  float sx = 0.f, sy = 0.f, sz = 0.f, sw = 0.f;
#pragma unroll
  for (int p = 0; p < KS1; ++p) {
    const float* sp = hpart + (size_t)(i + p * P4) * 4;
    sx += __builtin_nontemporal_load(sp + 0);
    sy += __builtin_nontemporal_load(sp + 1);
    sz += __builtin_nontemporal_load(sp + 2);
    sw += __builtin_nontemporal_load(sp + 3);
  }
  float4 bb = reinterpret_cast<const float4*>(bias1)[i & 3];
  float4 r;
  r.x = fmaxf(sx + bb.x, 0.f);
  r.y = fmaxf(sy + bb.y, 0.f);
  r.z = fmaxf(sz + bb.z, 0.f);
  r.w = fmaxf(sw + bb.w, 0.f);
  reinterpret_cast<float4*>(h)[i] = r;
}

// ---------------------------------------------------------------------------
// K8: layer 2. KS2=4 single dispatch (3128 blocks) + 2-edge unroll.
//     psort makes per-lane p near-uniform -> w2s LDS reads broadcast.
// ---------------------------------------------------------------------------
__device__ __forceinline__ void l2_accum(float* op, float v, float4 h0,
                                         float4 h1, float4 h2, float4 h3,
                                         const float* w2s, int p) {
  const float4* wp = reinterpret_cast<const float4*>(w2s + p * 132);
#pragma unroll
  for (int c = 0; c < 8; ++c) {
    float4 aq = wp[c * 4 + 0];
    float4 bq = wp[c * 4 + 1];
    float4 cq = wp[c * 4 + 2];
    float4 dq = wp[c * 4 + 3];
    float s = h0.x * aq.x + h0.y * aq.y + h0.z * aq.z + h0.w * aq.w
            + h1.x * bq.x + h1.y * bq.y + h1.z * bq.z + h1.w * bq.w
            + h2.x * cq.x + h2.y * cq.y + h2.z * cq.z + h2.w * cq.w
            + h3.x * dq.x + h3.y * dq.y + h3.z * dq.z + h3.w * dq.w;
    atomicAdd(op + c, v * s);
  }
}

__global__ __launch_bounds__(256) void layer2_kernel(
    const float* __restrict__ h, const float* __restrict__ W2g,
    const int* __restrict__ gstart, const int2* __restrict__ packed,
    float* __restrict__ opart) {
  __shared__ float w2s[R * 132];
  __shared__ float oacc[BKN * 9];
  for (int i = threadIdx.x; i < R * E * C; i += 256) {
    int p = i >> 7, ec = i & 127;     // W2g layout [p][e][c]
    int e = ec >> 3, c = ec & 7;
    w2s[p * 132 + c * 16 + e] = W2g[i];
  }
  for (int i = threadIdx.x; i < BKN * 9; i += 256) oacc[i] = 0.f;
  __syncthreads();
  int bkt = blockIdx.x >> 2, part = blockIdx.x & (KS2 - 1);
  int lo = gstart[bkt], len = gstart[bkt + 1] - lo;
  int a = lo + ((len * part) >> 2), b = lo + ((len * (part + 1)) >> 2);
  int plen = b - a;
  const float4* H4 = reinterpret_cast<const float4*>(h);
  const long long* pk8 = reinterpret_cast<const long long*>(packed);
  for (int e = a + 2 * (int)threadIdx.x; e + 1 < b; e += 512) {
    long long r0 = __builtin_nontemporal_load(pk8 + e);
    long long r1 = __builtin_nontemporal_load(pk8 + e + 1);
    int m0 = (int)r0, m1 = (int)r1;
    int col0 = m0 & CMASK, col1 = m1 & CMASK;
    int p0 = (int)((unsigned)col0 / (unsigned)N);
    int o0 = col0 - p0 * N;
    int p1 = (int)((unsigned)col1 / (unsigned)N);
    int o1 = col1 - p1 * N;
    float4 a0 = H4[o0 * 4 + 0], a1 = H4[o0 * 4 + 1];
    float4 a2 = H4[o0 * 4 + 2], a3 = H4[o0 * 4 + 3];
    float4 b0 = H4[o1 * 4 + 0], b1 = H4[o1 * 4 + 1];
    float4 b2 = H4[o1 * 4 + 2], b3 = H4[o1 * 4 + 3];
    l2_accum(&oacc[(((unsigned)m0) >> 26) * 9], __int_as_float((int)(r0 >> 32)),
             a0, a1, a2, a3, w2s, p0);
    l2_accum(&oacc[(((unsigned)m1) >> 26) * 9], __int_as_float((int)(r1 >> 32)),
             b0, b1, b2, b3, w2s, p1);
  }
  int m = a + ((plen >> 1) << 1);
  for (int e = m + (int)threadIdx.x; e < b; e += 256) {
    long long r0 = __builtin_nontemporal_load(pk8 + e);
    int m0 = (int)r0;
    int col0 = m0 & CMASK;
    int p0 = (int)((unsigned)col0 / (unsigned)N);
    int o0 = col0 - p0 * N;
    float4 a0 = H4[o0 * 4 + 0], a1 = H4[o0 * 4 + 1];
    float4 a2 = H4[o0 * 4 + 2], a3 = H4[o0 * 4 + 3];
    l2_accum(&oacc[(((unsigned)m0) >> 26) * 9], __int_as_float((int)(r0 >> 32)),
             a0, a1, a2, a3, w2s, p0);
  }
  __syncthreads();
  float* dst = opart + (size_t)part * (NPAD * C) + ((size_t)bkt << BSH) * C;
  for (int i = threadIdx.x; i < BKN * C; i += 256) {
    int slo = i >> 3, c = i & 7;
    __builtin_nontemporal_store(oacc[slo * 9 + c], dst + i);
  }
}

// ---------------------------------------------------------------------------
// K9: out = sum over 4 parts of opart + bias2
// ---------------------------------------------------------------------------
__global__ __launch_bounds__(256) void out_kernel(
    const float* __restrict__ opart, const float* __restrict__ bias2,
    float* __restrict__ out) {
  int i = blockIdx.x * 256 + threadIdx.x;
  if (i >= N * C / 4) return;
  constexpr int P4 = NPAD * C / 4;
  float sx = 0.f, sy = 0.f, sz = 0.f, sw = 0.f;
#pragma unroll
  for (int p = 0; p < KS2; ++p) {
    const float* sp = opart + (size_t)(i + p * P4) * 4;
    sx += __builtin_nontemporal_load(sp + 0);
    sy += __builtin_nontemporal_load(sp + 1);
    sz += __builtin_nontemporal_load(sp + 2);
    sw += __builtin_nontemporal_load(sp + 3);
  }
  float4 bb = reinterpret_cast<const float4*>(bias2)[i & 1];
  float4 r;
  r.x = sx + bb.x;
  r.y = sy + bb.y;
  r.z = sz + bb.z;
  r.w = sw + bb.w;
  reinterpret_cast<float4*>(out)[i] = r;
}

// ---------------------------------------------------------------------------
extern "C" void kernel_launch(void* const* d_in, const int* in_sizes, int n_in,
                              void* d_out, int out_size, void* d_ws, size_t ws_size,
                              hipStream_t stream) {
  const float* values  = (const float*)d_in[0];
  const float* comps1  = (const float*)d_in[1];
  const float* bases1  = (const float*)d_in[2];
  const float* comps2  = (const float*)d_in[3];
  const float* bases2  = (const float*)d_in[4];
  const float* bias1   = (const float*)d_in[5];
  const float* bias2   = (const float*)d_in[6];
  const int* hor_rows  = (const int*)d_in[7];
  const int* hor_cols  = (const int*)d_in[8];
  float* out = (float*)d_out;

  char* ws = (char*)d_ws;
  size_t off = 0;
  auto alloc = [&](size_t bytes) {
    void* p = ws + off;
    off += (bytes + 255) & ~size_t(255);
    return p;
  };
  unsigned* W1u    = (unsigned*)alloc((size_t)R * N * E / 2 * 4);   // 81.6 MB
  float*    h      = (float*)alloc((size_t)N * E * 4);              // 3.2 MB
  float*    W2g    = (float*)alloc((size_t)R * E * C * 4);
  int*      gcount = (int*)alloc((size_t)NB * 4);
  int*      gstart = (int*)alloc((size_t)(NB + 1) * 4);
  int*      gcursor= (int*)alloc((size_t)NB * 4);
  int2*     packed = (int2*)alloc((size_t)NNZ * 8);                 // 12.8 MB
  float*    hpart  = (float*)alloc((size_t)KS1 * NPAD * E * 4);     // 25.6 MB
  float*    opart  = (float*)alloc((size_t)KS2 * NPAD * C * 4);     // 6.4 MB
  (void)ws_size; (void)in_sizes; (void)n_in; (void)out_size;

  hipMemsetAsync(gcount, 0, (size_t)NB * 4, stream);

  count_kernel<<<CBLK, 256, 0, stream>>>(hor_rows, gcount);
  scan_kernel<<<1, 1024, 0, stream>>>(gcount, gstart, gcursor);
  scatter_kernel<<<SBLK, 1024, 0, stream>>>(hor_rows, hor_cols, values, gcursor,
                                            packed);
  psort_kernel<<<NB, 256, 0, stream>>>(gstart, (long long*)packed);
  w2_gemm_kernel<<<(R * E * C + 255) / 256, 256, 0, stream>>>(comps2, bases2, W2g);
  w1_gemm_kernel<<<(N * E / 2 + 255) / 256, 256, 0, stream>>>(comps1, bases1, W1u);
  layer1_kernel<<<NB * KS1, 256, 0, stream>>>(W1u, gstart, packed, hpart);
  relu_kernel<<<(N * E / 4 + 255) / 256, 256, 0, stream>>>(hpart, bias1, h);
  layer2_kernel<<<NB * KS2, 256, 0, stream>>>(h, W2g, gstart, packed, opart);
  out_kernel<<<(N * C / 4 + 255) / 256, 256, 0, stream>>>(opart, bias2, out);
}